// Round 2
// baseline (86784.479 us; speedup 1.0000x reference)
//
#include <hip/hip_runtime.h>

#define Tn 512
#define Bn 256
#define Hn 512
#define INn 512
#define TPB 512

typedef __attribute__((ext_vector_type(8))) short bf16x8;
typedef __attribute__((ext_vector_type(4))) float f32x4;

__device__ __forceinline__ unsigned short f2bf(float f) {
  unsigned int u = __float_as_uint(f);
  unsigned int r = (u + 0x7fffu + ((u >> 16) & 1u)) >> 16;
  return (unsigned short)r;
}

__device__ __forceinline__ float sigm(float x) { return 1.0f / (1.0f + __expf(-x)); }
__device__ __forceinline__ float tanh_f(float x) { return 2.0f / (1.0f + __expf(-2.0f * x)) - 1.0f; }

__device__ __forceinline__ bf16x8 ld8(const unsigned short* p) {
  return *reinterpret_cast<const bf16x8*>(p);
}

__device__ __forceinline__ f32x4 mfma16(bf16x8 a, bf16x8 b, f32x4 c) {
  return __builtin_amdgcn_mfma_f32_16x16x32_bf16(a, b, c, 0, 0, 0);
}

// ---------------- fp32 -> bf16 conversion ----------------
__global__ __launch_bounds__(256) void cvt_kernel(const float* __restrict__ in,
                                                  unsigned short* __restrict__ out, int n) {
  const int stride = gridDim.x * blockDim.x * 4;
  for (int i = (blockIdx.x * blockDim.x + threadIdx.x) * 4; i < n; i += stride) {
    float4 v = *reinterpret_cast<const float4*>(in + i);
    ushort4 o;
    o.x = f2bf(v.x); o.y = f2bf(v.y); o.z = f2bf(v.z); o.w = f2bf(v.w);
    *reinterpret_cast<ushort4*>(out + i) = o;
  }
}

// ---------------- XP = x @ Wx.T + folded biases (unchanged from round 0) ----------------
__global__ __launch_bounds__(256) void xp_gemm_kernel(
    const unsigned short* __restrict__ xb,
    const unsigned short* __restrict__ Wxb,
    const float* __restrict__ bx,
    const float* __restrict__ bh,
    const float* __restrict__ bgh,
    float* __restrict__ XP) {
  const int m0 = blockIdx.x * 64;
  const int n0 = blockIdx.y * 64;
  const int wave = threadIdx.x >> 6;
  const int lane = threadIdx.x & 63;
  const int l15 = lane & 15;
  const int lk = (lane >> 4) * 8;
  const int ro = (wave >> 1) * 32;
  const int co = (wave & 1) * 32;
  const unsigned short* ap = xb + (size_t)(m0 + ro + l15) * INn + lk;
  const unsigned short* bp = Wxb + (size_t)(n0 + co + l15) * INn + lk;
  f32x4 acc[2][2] = {};
  for (int k = 0; k < INn; k += 32) {
    bf16x8 a0 = ld8(ap + k);
    bf16x8 a1 = ld8(ap + 16 * INn + k);
    bf16x8 w0 = ld8(bp + k);
    bf16x8 w1 = ld8(bp + 16 * INn + k);
    acc[0][0] = mfma16(a0, w0, acc[0][0]);
    acc[0][1] = mfma16(a0, w1, acc[0][1]);
    acc[1][0] = mfma16(a1, w0, acc[1][0]);
    acc[1][1] = mfma16(a1, w1, acc[1][1]);
  }
#pragma unroll
  for (int rt = 0; rt < 2; ++rt)
#pragma unroll
    for (int ct = 0; ct < 2; ++ct) {
      const int col = n0 + co + ct * 16 + l15;
      float bias = bx[col];
      if (col < 1024) bias += bh[col] + bgh[col];
      else if (col >= 1536) bias += bh[col - 512] + bgh[col - 512];
#pragma unroll
      for (int r = 0; r < 4; ++r) {
        const int row = m0 + ro + rt * 16 + (lane >> 4) * 4 + r;
        XP[(size_t)row * 2048 + col] = acc[rt][ct][r] + bias;
      }
    }
}

// ---------------- persistent recurrence kernel ----------------
// grid = 256 blocks x 512 threads. Block: group = blockIdx&7 (b-rows [grp*32,+32)),
// jblk = blockIdx>>3 (j-slice of 16). Groups sync independently (32 blocks each,
// same XCD under round-robin dispatch). Weights for this j-slice live in LDS
// (XOR-swizzled vs 1024B-stride bank conflicts). h/g fp32 masters in registers.
__device__ __forceinline__ void group_barrier(unsigned int* cnt, unsigned int target) {
  __threadfence();
  __syncthreads();
  if (threadIdx.x == 0) {
    __hip_atomic_fetch_add(cnt, 1u, __ATOMIC_RELEASE, __HIP_MEMORY_SCOPE_AGENT);
    while (__hip_atomic_load(cnt, __ATOMIC_ACQUIRE, __HIP_MEMORY_SCOPE_AGENT) < target)
      __builtin_amdgcn_s_sleep(1);
  }
  __syncthreads();
  __threadfence();
}

__global__ __launch_bounds__(512, 2) void persist_kernel(
    const unsigned short* __restrict__ Whb,
    const unsigned short* __restrict__ Wghb,
    const unsigned short* __restrict__ Whdb,
    const unsigned short* __restrict__ Wgb,
    const float* __restrict__ XP,          // (Tc*256, 2048), biases folded
    const float* __restrict__ bhd,
    const float* __restrict__ bg,
    unsigned short* __restrict__ hb0,      // 2 ping-pong slots of 256*512
    unsigned short* __restrict__ gb,
    unsigned short* __restrict__ hdb,
    float* __restrict__ g_master,
    const float* __restrict__ h0,
    const float* __restrict__ g0,
    float* __restrict__ hs,                // d_out (T,B,H)
    float* __restrict__ h_tail,
    float* __restrict__ g_tail,
    unsigned int* __restrict__ barcnt,     // 8 counters for this chunk
    int t0, int Tc) {
  __shared__ unsigned short Wh_l[48 * 512];
  __shared__ unsigned short Wgh_l[48 * 512];
  __shared__ unsigned short Whd_l[32 * 512];
  __shared__ float pa[8][32][17];
  __shared__ float xp_l[4][32][17];

  const int tid = threadIdx.x;
  const int grp = blockIdx.x & 7;
  const int jblk = blockIdx.x >> 3;
  const int j0 = jblk * 16;
  const int b0 = grp * 32;
  const int wv = tid >> 6;
  const int lane = tid & 63;
  const int l15 = lane & 15;
  const int lk = (lane >> 4) * 8;
  unsigned int* cnt = barcnt + grp;

  // ---- stage weights into LDS (swizzled: byte ^= (row&7)<<4) ----
  for (int i = tid; i < 48 * 64; i += TPB) {
    const int rr = i >> 6, c = i & 63;
    const int grow = (rr >> 4) * 512 + j0 + (rr & 15);
    const int byte = rr * 1024 + ((c * 16) ^ ((rr & 7) << 4));
    *reinterpret_cast<uint4*>(reinterpret_cast<char*>(Wh_l) + byte) =
        *reinterpret_cast<const uint4*>(Whb + (size_t)grow * 512 + c * 8);
    *reinterpret_cast<uint4*>(reinterpret_cast<char*>(Wgh_l) + byte) =
        *reinterpret_cast<const uint4*>(Wghb + (size_t)grow * 512 + c * 8);
  }
  for (int i = tid; i < 32 * 64; i += TPB) {
    const int rr = i >> 6, c = i & 63;
    const int grow = (rr >> 4) * 512 + j0 + (rr & 15);
    const int byte = rr * 1024 + ((c * 16) ^ ((rr & 7) << 4));
    *reinterpret_cast<uint4*>(reinterpret_cast<char*>(Whd_l) + byte) =
        *reinterpret_cast<const uint4*>(Whdb + (size_t)grow * 512 + c * 8);
  }

  // ---- per-thread persistent state ----
  const int bl_e = tid >> 4, jl_e = tid & 15;
  const int j_e = j0 + jl_e;
  const size_t o_e = (size_t)(b0 + bl_e) * Hn + j_e;
  float h_m = (t0 == 0) ? h0[o_e] : hs[(size_t)(t0 - 1) * (Bn * Hn) + o_e];
  float g_m = (t0 == 0) ? g0[o_e] : g_master[o_e];
  const float bz2 = bhd[j_e] + bg[j_e];
  const float br2 = bhd[512 + j_e] + bg[512 + j_e];
  const float bgc = bhd[1024 + j_e];

  // preload XP(step 0 of chunk)
  for (int i = tid; i < 2048; i += TPB) {
    const int gate = i >> 9, bb = (i >> 4) & 31, jj = i & 15;
    xp_l[gate][bb][jj] = XP[(size_t)(b0 + bb) * 2048 + gate * 512 + j0 + jj];
  }
  __syncthreads();

  unsigned int nbar = 0;
  float z2p = 0.0f, r2p = 0.0f;

  for (int tt = 0; tt < Tc; ++tt) {
    const int t = t0 + tt;
    const unsigned short* hb_cur = hb0 + (size_t)(t & 1) * (Bn * Hn);
    unsigned short* hb_nxt = hb0 + (size_t)((t + 1) & 1) * (Bn * Hn);

    // ---------- phase A GEMMs ----------
    if (wv <= 1) {
      // wv0: h @ Wh.T (z,r,u) -> pa[0..2]; wv1: g @ Wgh.T -> pa[3..5]
      const unsigned short* Ab = (wv == 0) ? hb_cur : gb;
      const unsigned short* Wl = (wv == 0) ? Wh_l : Wgh_l;
      const unsigned short* ap0 = Ab + (size_t)(b0 + l15) * Hn + lk;
      f32x4 acc[2][3] = {};
      for (int kt = 0; kt < 16; ++kt) {
        const int k = kt * 32;
        bf16x8 a0 = ld8(ap0 + k);
        bf16x8 a1 = ld8(ap0 + 16 * Hn + k);
#pragma unroll
        for (int s = 0; s < 3; ++s) {
          const int rr = s * 16 + l15;
          const int byte = rr * 1024 + (((k + lk) * 2) ^ ((rr & 7) << 4));
          bf16x8 bf = *reinterpret_cast<const bf16x8*>(
              reinterpret_cast<const char*>(Wl) + byte);
          acc[0][s] = mfma16(a0, bf, acc[0][s]);
          acc[1][s] = mfma16(a1, bf, acc[1][s]);
        }
      }
      const int pb = (wv == 0) ? 0 : 3;
#pragma unroll
      for (int s = 0; s < 3; ++s)
#pragma unroll
        for (int rt = 0; rt < 2; ++rt)
#pragma unroll
          for (int r = 0; r < 4; ++r)
            pa[pb + s][rt * 16 + (lane >> 4) * 4 + r][l15] = acc[rt][s][r];
    } else if (wv == 2) {
      // g @ Wg.T (z2,r2) -> pa[6..7]  (Wg streamed from L2)
      const unsigned short* ap0 = gb + (size_t)(b0 + l15) * Hn + lk;
      const unsigned short* bp0 = Wgb + (size_t)(j0 + l15) * Hn + lk;
      const unsigned short* bp1 = Wgb + (size_t)(512 + j0 + l15) * Hn + lk;
      f32x4 acc[2][2] = {};
      for (int kt = 0; kt < 16; ++kt) {
        const int k = kt * 32;
        bf16x8 a0 = ld8(ap0 + k);
        bf16x8 a1 = ld8(ap0 + 16 * Hn + k);
        bf16x8 w0 = ld8(bp0 + k);
        bf16x8 w1 = ld8(bp1 + k);
        acc[0][0] = mfma16(a0, w0, acc[0][0]);
        acc[1][0] = mfma16(a1, w0, acc[1][0]);
        acc[0][1] = mfma16(a0, w1, acc[0][1]);
        acc[1][1] = mfma16(a1, w1, acc[1][1]);
      }
#pragma unroll
      for (int s = 0; s < 2; ++s)
#pragma unroll
        for (int rt = 0; rt < 2; ++rt)
#pragma unroll
          for (int r = 0; r < 4; ++r)
            pa[6 + s][rt * 16 + (lane >> 4) * 4 + r][l15] = acc[rt][s][r];
    }
    __syncthreads();

    // ---------- elementwise h update ----------
    {
      const float z = sigm(xp_l[0][bl_e][jl_e] + pa[0][bl_e][jl_e] + pa[3][bl_e][jl_e]);
      const float r = sigm(xp_l[1][bl_e][jl_e] + pa[1][bl_e][jl_e] + pa[4][bl_e][jl_e]);
      const float u = sigm(xp_l[3][bl_e][jl_e] + pa[2][bl_e][jl_e] + pa[5][bl_e][jl_e]);
      const float cand = tanh_f(xp_l[2][bl_e][jl_e] + r * h_m + u * g_m);
      const float hn = (1.0f - z) * h_m + z * cand;
      const float hd = hn - h_m;
      hs[(size_t)t * (Bn * Hn) + o_e] = hn;
      if (t == Tn - 1) h_tail[o_e] = hn;
      hb_nxt[o_e] = f2bf(hn);
      hdb[o_e] = f2bf(hd);
      h_m = hn;
      z2p = pa[6][bl_e][jl_e];
      r2p = pa[7][bl_e][jl_e];
    }
    group_barrier(cnt, 32u * (++nbar));

    // ---------- phase B GEMMs ----------
    if (wv == 0) {
      // hd @ Whd.T (z2,r2 gates) -> pa[0..1]
      const unsigned short* ap0 = hdb + (size_t)(b0 + l15) * Hn + lk;
      f32x4 acc[2][2] = {};
      for (int kt = 0; kt < 16; ++kt) {
        const int k = kt * 32;
        bf16x8 a0 = ld8(ap0 + k);
        bf16x8 a1 = ld8(ap0 + 16 * Hn + k);
#pragma unroll
        for (int s = 0; s < 2; ++s) {
          const int rr = s * 16 + l15;
          const int byte = rr * 1024 + (((k + lk) * 2) ^ ((rr & 7) << 4));
          bf16x8 bf = *reinterpret_cast<const bf16x8*>(
              reinterpret_cast<const char*>(Whd_l) + byte);
          acc[0][s] = mfma16(a0, bf, acc[0][s]);
          acc[1][s] = mfma16(a1, bf, acc[1][s]);
        }
      }
#pragma unroll
      for (int s = 0; s < 2; ++s)
#pragma unroll
        for (int rt = 0; rt < 2; ++rt)
#pragma unroll
          for (int r = 0; r < 4; ++r)
            pa[s][rt * 16 + (lane >> 4) * 4 + r][l15] = acc[rt][s][r];
    } else if (wv == 1) {
      // hd @ Whd.T (g-candidate gate, streamed) -> pa[2]
      const unsigned short* ap0 = hdb + (size_t)(b0 + l15) * Hn + lk;
      const unsigned short* bp0 = Whdb + (size_t)(1024 + j0 + l15) * Hn + lk;
      f32x4 acc[2] = {};
      for (int kt = 0; kt < 16; ++kt) {
        const int k = kt * 32;
        bf16x8 a0 = ld8(ap0 + k);
        bf16x8 a1 = ld8(ap0 + 16 * Hn + k);
        bf16x8 w0 = ld8(bp0 + k);
        acc[0] = mfma16(a0, w0, acc[0]);
        acc[1] = mfma16(a1, w0, acc[1]);
      }
#pragma unroll
      for (int rt = 0; rt < 2; ++rt)
#pragma unroll
        for (int r = 0; r < 4; ++r)
          pa[2][rt * 16 + (lane >> 4) * 4 + r][l15] = acc[rt][r];
    } else if (tt + 1 < Tc) {
      // prefetch next step's XP slice into LDS
      for (int i = tid - 128; i < 2048; i += 384) {
        const int gate = i >> 9, bb = (i >> 4) & 31, jj = i & 15;
        xp_l[gate][bb][jj] =
            XP[(size_t)((tt + 1) * Bn + b0 + bb) * 2048 + gate * 512 + j0 + jj];
      }
    }
    __syncthreads();

    // ---------- elementwise g update ----------
    {
      const float z2 = sigm(pa[0][bl_e][jl_e] + z2p + bz2);
      const float r2 = sigm(pa[1][bl_e][jl_e] + r2p + br2);
      const float gc = tanh_f(pa[2][bl_e][jl_e] + bgc + r2 * g_m);
      const float gn = (1.0f - z2) * g_m + z2 * gc;
      g_m = gn;
      gb[o_e] = f2bf(gn);
      if (t == Tn - 1) g_tail[o_e] = gn;
    }
    group_barrier(cnt, 32u * (++nbar));
  }
  g_master[o_e] = g_m;
}

// ---------------- host ----------------
extern "C" void kernel_launch(void* const* d_in, const int* in_sizes, int n_in,
                              void* d_out, int out_size, void* d_ws, size_t ws_size,
                              hipStream_t stream) {
  const float* x   = (const float*)d_in[0];
  const float* h0  = (const float*)d_in[1];
  const float* g0  = (const float*)d_in[2];
  const float* Wx  = (const float*)d_in[3];
  const float* bx  = (const float*)d_in[4];
  const float* Wh  = (const float*)d_in[5];
  const float* bh  = (const float*)d_in[6];
  const float* Wgh = (const float*)d_in[7];
  const float* bgh = (const float*)d_in[8];
  const float* Whd = (const float*)d_in[9];
  const float* bhd = (const float*)d_in[10];
  const float* Wg  = (const float*)d_in[11];
  const float* bg  = (const float*)d_in[12];

  char* ws = (char*)d_ws;
  unsigned short* Whb  = (unsigned short*)(ws + 0);         // 1536x512
  unsigned short* Wghb = (unsigned short*)(ws + 1572864);
  unsigned short* Whdb = (unsigned short*)(ws + 3145728);
  unsigned short* Wgb  = (unsigned short*)(ws + 4718592);   // 1024x512
  unsigned short* Wxb  = (unsigned short*)(ws + 5767168);   // 2048x512
  unsigned short* hb0  = (unsigned short*)(ws + 7864320);   // 2 x 256x512
  unsigned short* gb_  = (unsigned short*)(ws + 8388608);
  unsigned short* hdb  = (unsigned short*)(ws + 8650752);
  float* g_master      = (float*)(ws + 8912896);            // 256x512 f32
  unsigned int* barcnt = (unsigned int*)(ws + 9437184);     // 16KB
  const size_t FIXED = 9453568ULL;

  int Tc = 64;
  while (Tc > 1 && FIXED + (size_t)Tc * (262144ULL + 2097152ULL) > ws_size) Tc >>= 1;
  unsigned short* xb = (unsigned short*)(ws + FIXED);
  float* XPc = (float*)(ws + FIXED + (size_t)Tc * 262144ULL);

  float* hs = (float*)d_out;
  float* h_tail = hs + (size_t)Tn * Bn * Hn;
  float* g_tail = h_tail + (size_t)Bn * Hn;

  hipMemsetAsync(barcnt, 0, 16384, stream);
  cvt_kernel<<<dim3(512), 256, 0, stream>>>(Wh, Whb, 1536 * 512);
  cvt_kernel<<<dim3(512), 256, 0, stream>>>(Wgh, Wghb, 1536 * 512);
  cvt_kernel<<<dim3(512), 256, 0, stream>>>(Whd, Whdb, 1536 * 512);
  cvt_kernel<<<dim3(512), 256, 0, stream>>>(Wg, Wgb, 1024 * 512);
  cvt_kernel<<<dim3(512), 256, 0, stream>>>(Wx, Wxb, 2048 * 512);
  cvt_kernel<<<dim3(128), 256, 0, stream>>>(h0, hb0, Bn * Hn);  // slot 0 (t=0 reads hb[0])
  cvt_kernel<<<dim3(128), 256, 0, stream>>>(g0, gb_, Bn * Hn);

  const int nChunks = Tn / Tc;
  for (int c = 0; c < nChunks; ++c) {
    const int t0 = c * Tc;
    cvt_kernel<<<dim3(1024), 256, 0, stream>>>(x + (size_t)t0 * Bn * INn, xb,
                                               Tc * Bn * INn);
    xp_gemm_kernel<<<dim3(Tc * 4, 32), 256, 0, stream>>>(xb, Wxb, bx, bh, bgh, XPc);
    persist_kernel<<<dim3(256), dim3(TPB), 0, stream>>>(
        Whb, Wghb, Whdb, Wgb, XPc, bhd, bg, hb0, gb_, hdb, g_master, h0, g0,
        hs, h_tail, g_tail, barcnt + c * 8, t0, Tc);
  }
}

// Round 3
// 9840.987 us; speedup vs baseline: 8.8187x; 8.8187x over previous
//
#include <hip/hip_runtime.h>

#define Tn 512
#define Bn 256
#define Hn 512
#define INn 512
#define TPB 512

typedef __attribute__((ext_vector_type(8))) short bf16x8;
typedef __attribute__((ext_vector_type(4))) float f32x4;

__device__ __forceinline__ unsigned short f2bf(float f) {
  unsigned int u = __float_as_uint(f);
  unsigned int r = (u + 0x7fffu + ((u >> 16) & 1u)) >> 16;
  return (unsigned short)r;
}

__device__ __forceinline__ float sigm(float x) { return 1.0f / (1.0f + __expf(-x)); }
__device__ __forceinline__ float tanh_f(float x) { return 2.0f / (1.0f + __expf(-2.0f * x)) - 1.0f; }

__device__ __forceinline__ bf16x8 ld8(const unsigned short* p) {
  return *reinterpret_cast<const bf16x8*>(p);
}

// coherent (LLC-homed, cache-bypassing) loads/stores: relaxed agent scope ->
// sc0 sc1 flagged ops, NO cache maintenance instructions.
__device__ __forceinline__ unsigned long long ald8(const unsigned short* p) {
  return __hip_atomic_load((const unsigned long long*)p, __ATOMIC_RELAXED,
                           __HIP_MEMORY_SCOPE_AGENT);
}
__device__ __forceinline__ bf16x8 ald16(const unsigned short* p) {
  union { unsigned long long u[2]; bf16x8 v; } r;
  r.u[0] = ald8(p);
  r.u[1] = ald8(p + 4);
  return r.v;
}
__device__ __forceinline__ void ast4(unsigned short* p, unsigned int v) {
  __hip_atomic_store((unsigned int*)p, v, __ATOMIC_RELAXED, __HIP_MEMORY_SCOPE_AGENT);
}

__device__ __forceinline__ f32x4 mfma16(bf16x8 a, bf16x8 b, f32x4 c) {
  return __builtin_amdgcn_mfma_f32_16x16x32_bf16(a, b, c, 0, 0, 0);
}

// ---------------- fp32 -> bf16 conversion ----------------
__global__ __launch_bounds__(256) void cvt_kernel(const float* __restrict__ in,
                                                  unsigned short* __restrict__ out, int n) {
  const int stride = gridDim.x * blockDim.x * 4;
  for (int i = (blockIdx.x * blockDim.x + threadIdx.x) * 4; i < n; i += stride) {
    float4 v = *reinterpret_cast<const float4*>(in + i);
    ushort4 o;
    o.x = f2bf(v.x); o.y = f2bf(v.y); o.z = f2bf(v.z); o.w = f2bf(v.w);
    *reinterpret_cast<ushort4*>(out + i) = o;
  }
}

// ---------------- XP = x @ Wx.T + folded biases ----------------
__global__ __launch_bounds__(256) void xp_gemm_kernel(
    const unsigned short* __restrict__ xb,
    const unsigned short* __restrict__ Wxb,
    const float* __restrict__ bx,
    const float* __restrict__ bh,
    const float* __restrict__ bgh,
    float* __restrict__ XP) {
  const int m0 = blockIdx.x * 64;
  const int n0 = blockIdx.y * 64;
  const int wave = threadIdx.x >> 6;
  const int lane = threadIdx.x & 63;
  const int l15 = lane & 15;
  const int lk = (lane >> 4) * 8;
  const int ro = (wave >> 1) * 32;
  const int co = (wave & 1) * 32;
  const unsigned short* ap = xb + (size_t)(m0 + ro + l15) * INn + lk;
  const unsigned short* bp = Wxb + (size_t)(n0 + co + l15) * INn + lk;
  f32x4 acc[2][2] = {};
  for (int k = 0; k < INn; k += 32) {
    bf16x8 a0 = ld8(ap + k);
    bf16x8 a1 = ld8(ap + 16 * INn + k);
    bf16x8 w0 = ld8(bp + k);
    bf16x8 w1 = ld8(bp + 16 * INn + k);
    acc[0][0] = mfma16(a0, w0, acc[0][0]);
    acc[0][1] = mfma16(a0, w1, acc[0][1]);
    acc[1][0] = mfma16(a1, w0, acc[1][0]);
    acc[1][1] = mfma16(a1, w1, acc[1][1]);
  }
#pragma unroll
  for (int rt = 0; rt < 2; ++rt)
#pragma unroll
    for (int ct = 0; ct < 2; ++ct) {
      const int col = n0 + co + ct * 16 + l15;
      float bias = bx[col];
      if (col < 1024) bias += bh[col] + bgh[col];
      else if (col >= 1536) bias += bh[col - 512] + bgh[col - 512];
#pragma unroll
      for (int r = 0; r < 4; ++r) {
        const int row = m0 + ro + rt * 16 + (lane >> 4) * 4 + r;
        XP[(size_t)row * 2048 + col] = acc[rt][ct][r] + bias;
      }
    }
}

// ---------------- persistent recurrence kernel ----------------
// grid=256 x 512thr. group = blockIdx&7 (32 b-rows), jblk = blockIdx>>3 (16 cols).
// Fence-free group barrier: syncthreads (drains write-through stores via vmcnt0)
// -> relaxed agent fetch_add -> relaxed spin -> syncthreads. No L2 inv/wb ever.
__device__ __forceinline__ void group_barrier(unsigned int* cnt, unsigned int target) {
  __syncthreads();
  if (threadIdx.x == 0) {
    __hip_atomic_fetch_add(cnt, 1u, __ATOMIC_RELAXED, __HIP_MEMORY_SCOPE_AGENT);
    while (__hip_atomic_load(cnt, __ATOMIC_RELAXED, __HIP_MEMORY_SCOPE_AGENT) < target)
      __builtin_amdgcn_s_sleep(1);
  }
  __syncthreads();
}

// stage 32 rows x 512 cols bf16 from a coherent buffer into swizzled LDS
__device__ __forceinline__ void stage_A(const unsigned short* src,
                                        unsigned short* dst_l, int b0, int tid) {
  const int rr = tid >> 4;         // 0..31
  const int cu = (tid & 15) * 8;   // ull index in row, 8 per thread
  const unsigned short* s = src + (size_t)(b0 + rr) * Hn + cu * 4;
  char* dbase = (char*)dst_l + rr * 1024;
  const int swz = (rr & 7) << 4;
#pragma unroll
  for (int q = 0; q < 8; ++q) {
    unsigned long long v = ald8(s + q * 4);
    *(unsigned long long*)(dbase + (((cu + q) * 8) ^ swz)) = v;
  }
}

__global__ __launch_bounds__(512, 1) void persist_kernel(
    const unsigned short* __restrict__ Whb,
    const unsigned short* __restrict__ Wghb,
    const unsigned short* __restrict__ Whdb,
    const unsigned short* __restrict__ Wgb,
    const float* __restrict__ XP,
    const float* __restrict__ bhd,
    const float* __restrict__ bg,
    unsigned short* __restrict__ hb0,      // 2 ping-pong slots of 256*512
    unsigned short* __restrict__ gb,
    unsigned short* __restrict__ hdb,
    float* __restrict__ g_master,
    const float* __restrict__ h0,
    const float* __restrict__ g0,
    float* __restrict__ hs,
    float* __restrict__ h_tail,
    float* __restrict__ g_tail,
    unsigned int* __restrict__ barcnt,
    int t0, int Tc) {
  __shared__ unsigned short Wh_l[48 * 512];    // 48KB, swizzled
  __shared__ unsigned short Wgh_l[48 * 512];   // 48KB, swizzled
  __shared__ unsigned short As_l[32 * 512];    // 32KB staging (gb / hdb)
  __shared__ float pa[8][32][17];
  __shared__ float xp_l[4][32][17];

  const int tid = threadIdx.x;
  const int grp = blockIdx.x & 7;
  const int jblk = blockIdx.x >> 3;
  const int j0 = jblk * 16;
  const int b0 = grp * 32;
  const int wv = tid >> 6;
  const int lane = tid & 63;
  const int l15 = lane & 15;
  const int lk = (lane >> 4) * 8;
  unsigned int* cnt = barcnt + grp;

  // ---- stage Wh, Wgh into LDS (swizzled: byte ^= (row&7)<<4) ----
  for (int i = tid; i < 48 * 64; i += TPB) {
    const int rr = i >> 6, c = i & 63;
    const int grow = (rr >> 4) * 512 + j0 + (rr & 15);
    const int byte = rr * 1024 + ((c * 16) ^ ((rr & 7) << 4));
    *reinterpret_cast<uint4*>(reinterpret_cast<char*>(Wh_l) + byte) =
        *reinterpret_cast<const uint4*>(Whb + (size_t)grow * 512 + c * 8);
    *reinterpret_cast<uint4*>(reinterpret_cast<char*>(Wgh_l) + byte) =
        *reinterpret_cast<const uint4*>(Wghb + (size_t)grow * 512 + c * 8);
  }

  // ---- per-thread persistent state ----
  const int bl_e = tid >> 4, jl_e = tid & 15;
  const int j_e = j0 + jl_e;
  const size_t o_e = (size_t)(b0 + bl_e) * Hn + j_e;
  float h_m = (t0 == 0) ? h0[o_e] : hs[(size_t)(t0 - 1) * (Bn * Hn) + o_e];
  float g_m = (t0 == 0) ? g0[o_e] : g_master[o_e];
  const float bz2 = bhd[j_e] + bg[j_e];
  const float br2 = bhd[512 + j_e] + bg[512 + j_e];
  const float bgc = bhd[1024 + j_e];

  // preload XP(step 0 of chunk)
  for (int i = tid; i < 2048; i += TPB) {
    const int gate = i >> 9, bb = (i >> 4) & 31, jj = i & 15;
    xp_l[gate][bb][jj] = XP[(size_t)(b0 + bb) * 2048 + gate * 512 + j0 + jj];
  }
  __syncthreads();

  unsigned int nbar = 0;
  float z2p = 0.0f, r2p = 0.0f;
  const int swzA = (l15 & 7) << 4;

  for (int tt = 0; tt < Tc; ++tt) {
    const int t = t0 + tt;
    const unsigned short* hb_cur = hb0 + (size_t)(t & 1) * (Bn * Hn);
    unsigned short* hb_nxt = hb0 + (size_t)((t + 1) & 1) * (Bn * Hn);

    // ---- stage g(t-1) into LDS ----
    stage_A(gb, As_l, b0, tid);
    __syncthreads();

    // ---------- phase A GEMMs ----------
    if (wv == 0) {
      // h @ Wh.T (z,r,u), A streamed coherent from LLC
      const unsigned short* ap0 = hb_cur + (size_t)(b0 + l15) * Hn + lk;
      f32x4 acc[2][3] = {};
      for (int kt = 0; kt < 16; ++kt) {
        const int k = kt * 32;
        bf16x8 a0 = ald16(ap0 + k);
        bf16x8 a1 = ald16(ap0 + 16 * Hn + k);
#pragma unroll
        for (int s = 0; s < 3; ++s) {
          const int rr = s * 16 + l15;
          const int byte = rr * 1024 + (((k + lk) * 2) ^ swzA);
          bf16x8 bf = *reinterpret_cast<const bf16x8*>(
              reinterpret_cast<const char*>(Wh_l) + byte);
          acc[0][s] = mfma16(a0, bf, acc[0][s]);
          acc[1][s] = mfma16(a1, bf, acc[1][s]);
        }
      }
#pragma unroll
      for (int s = 0; s < 3; ++s)
#pragma unroll
        for (int rt = 0; rt < 2; ++rt)
#pragma unroll
          for (int r = 0; r < 4; ++r)
            pa[s][rt * 16 + (lane >> 4) * 4 + r][l15] = acc[rt][s][r];
    } else if (wv == 1) {
      // g @ Wgh.T (z,r,u), A from staged LDS
      f32x4 acc[2][3] = {};
      for (int kt = 0; kt < 16; ++kt) {
        const int k = kt * 32;
        const int abyte = (((k + lk) * 2) ^ swzA);
        bf16x8 a0 = *reinterpret_cast<const bf16x8*>(
            reinterpret_cast<const char*>(As_l) + l15 * 1024 + abyte);
        bf16x8 a1 = *reinterpret_cast<const bf16x8*>(
            reinterpret_cast<const char*>(As_l) + (16 + l15) * 1024 + abyte);
#pragma unroll
        for (int s = 0; s < 3; ++s) {
          const int rr = s * 16 + l15;
          const int byte = rr * 1024 + (((k + lk) * 2) ^ swzA);
          bf16x8 bf = *reinterpret_cast<const bf16x8*>(
              reinterpret_cast<const char*>(Wgh_l) + byte);
          acc[0][s] = mfma16(a0, bf, acc[0][s]);
          acc[1][s] = mfma16(a1, bf, acc[1][s]);
        }
      }
#pragma unroll
      for (int s = 0; s < 3; ++s)
#pragma unroll
        for (int rt = 0; rt < 2; ++rt)
#pragma unroll
          for (int r = 0; r < 4; ++r)
            pa[3 + s][rt * 16 + (lane >> 4) * 4 + r][l15] = acc[rt][s][r];
    } else if (wv == 2) {
      // g @ Wg.T (z2,r2), A from staged LDS, W streamed from L2
      const unsigned short* bp0 = Wgb + (size_t)(j0 + l15) * Hn + lk;
      const unsigned short* bp1 = Wgb + (size_t)(512 + j0 + l15) * Hn + lk;
      f32x4 acc[2][2] = {};
      for (int kt = 0; kt < 16; ++kt) {
        const int k = kt * 32;
        const int abyte = (((k + lk) * 2) ^ swzA);
        bf16x8 a0 = *reinterpret_cast<const bf16x8*>(
            reinterpret_cast<const char*>(As_l) + l15 * 1024 + abyte);
        bf16x8 a1 = *reinterpret_cast<const bf16x8*>(
            reinterpret_cast<const char*>(As_l) + (16 + l15) * 1024 + abyte);
        bf16x8 w0 = ld8(bp0 + k);
        bf16x8 w1 = ld8(bp1 + k);
        acc[0][0] = mfma16(a0, w0, acc[0][0]);
        acc[1][0] = mfma16(a1, w0, acc[1][0]);
        acc[0][1] = mfma16(a0, w1, acc[0][1]);
        acc[1][1] = mfma16(a1, w1, acc[1][1]);
      }
#pragma unroll
      for (int s = 0; s < 2; ++s)
#pragma unroll
        for (int rt = 0; rt < 2; ++rt)
#pragma unroll
          for (int r = 0; r < 4; ++r)
            pa[6 + s][rt * 16 + (lane >> 4) * 4 + r][l15] = acc[rt][s][r];
    }
    __syncthreads();

    // ---------- elementwise h update ----------
    {
      const float z = sigm(xp_l[0][bl_e][jl_e] + pa[0][bl_e][jl_e] + pa[3][bl_e][jl_e]);
      const float r = sigm(xp_l[1][bl_e][jl_e] + pa[1][bl_e][jl_e] + pa[4][bl_e][jl_e]);
      const float u = sigm(xp_l[3][bl_e][jl_e] + pa[2][bl_e][jl_e] + pa[5][bl_e][jl_e]);
      const float cand = tanh_f(xp_l[2][bl_e][jl_e] + r * h_m + u * g_m);
      const float hn = (1.0f - z) * h_m + z * cand;
      const float hd = hn - h_m;
      hs[(size_t)t * (Bn * Hn) + o_e] = hn;
      if (t == Tn - 1) h_tail[o_e] = hn;
      const unsigned int hn_u = f2bf(hn), hd_u = f2bf(hd);
      const unsigned int hn_hi = (unsigned int)__shfl_down((int)hn_u, 1);
      const unsigned int hd_hi = (unsigned int)__shfl_down((int)hd_u, 1);
      if ((jl_e & 1) == 0) {
        ast4(hb_nxt + o_e, hn_u | (hn_hi << 16));
        ast4(hdb + o_e, hd_u | (hd_hi << 16));
      }
      h_m = hn;
      z2p = pa[6][bl_e][jl_e];
      r2p = pa[7][bl_e][jl_e];
    }
    group_barrier(cnt, 32u * (++nbar));

    // ---- stage hd into LDS ----
    stage_A(hdb, As_l, b0, tid);
    __syncthreads();

    // ---------- phase B GEMMs: hd @ Whd.T (W streamed from L2) ----------
    if (wv < 3) {
      const unsigned short* bp0 = Whdb + (size_t)(wv * 512 + j0 + l15) * Hn + lk;
      f32x4 acc[2] = {};
      for (int kt = 0; kt < 16; ++kt) {
        const int k = kt * 32;
        const int abyte = (((k + lk) * 2) ^ swzA);
        bf16x8 a0 = *reinterpret_cast<const bf16x8*>(
            reinterpret_cast<const char*>(As_l) + l15 * 1024 + abyte);
        bf16x8 a1 = *reinterpret_cast<const bf16x8*>(
            reinterpret_cast<const char*>(As_l) + (16 + l15) * 1024 + abyte);
        bf16x8 w0 = ld8(bp0 + k);
        acc[0] = mfma16(a0, w0, acc[0]);
        acc[1] = mfma16(a1, w0, acc[1]);
      }
#pragma unroll
      for (int rt = 0; rt < 2; ++rt)
#pragma unroll
        for (int r = 0; r < 4; ++r)
          pa[wv][rt * 16 + (lane >> 4) * 4 + r][l15] = acc[rt][r];
    } else if (tt + 1 < Tc) {
      // XP prefetch for next step (waves 3..7)
      for (int i = tid - 192; i < 2048; i += 320) {
        const int gate = i >> 9, bb = (i >> 4) & 31, jj = i & 15;
        xp_l[gate][bb][jj] =
            XP[(size_t)((tt + 1) * Bn + b0 + bb) * 2048 + gate * 512 + j0 + jj];
      }
    }
    __syncthreads();

    // ---------- elementwise g update ----------
    {
      const float z2 = sigm(pa[0][bl_e][jl_e] + z2p + bz2);
      const float r2 = sigm(pa[1][bl_e][jl_e] + r2p + br2);
      const float gc = tanh_f(pa[2][bl_e][jl_e] + bgc + r2 * g_m);
      const float gn = (1.0f - z2) * g_m + z2 * gc;
      g_m = gn;
      if (t == Tn - 1) g_tail[o_e] = gn;
      const unsigned int gn_u = f2bf(gn);
      const unsigned int gn_hi = (unsigned int)__shfl_down((int)gn_u, 1);
      if ((jl_e & 1) == 0) ast4(gb + o_e, gn_u | (gn_hi << 16));
    }
    group_barrier(cnt, 32u * (++nbar));
  }
  g_master[o_e] = g_m;
}

// ---------------- host ----------------
extern "C" void kernel_launch(void* const* d_in, const int* in_sizes, int n_in,
                              void* d_out, int out_size, void* d_ws, size_t ws_size,
                              hipStream_t stream) {
  const float* x   = (const float*)d_in[0];
  const float* h0  = (const float*)d_in[1];
  const float* g0  = (const float*)d_in[2];
  const float* Wx  = (const float*)d_in[3];
  const float* bx  = (const float*)d_in[4];
  const float* Wh  = (const float*)d_in[5];
  const float* bh  = (const float*)d_in[6];
  const float* Wgh = (const float*)d_in[7];
  const float* bgh = (const float*)d_in[8];
  const float* Whd = (const float*)d_in[9];
  const float* bhd = (const float*)d_in[10];
  const float* Wg  = (const float*)d_in[11];
  const float* bg  = (const float*)d_in[12];

  char* ws = (char*)d_ws;
  unsigned short* Whb  = (unsigned short*)(ws + 0);
  unsigned short* Wghb = (unsigned short*)(ws + 1572864);
  unsigned short* Whdb = (unsigned short*)(ws + 3145728);
  unsigned short* Wgb  = (unsigned short*)(ws + 4718592);
  unsigned short* Wxb  = (unsigned short*)(ws + 5767168);
  unsigned short* hb0  = (unsigned short*)(ws + 7864320);   // 2 x 256x512
  unsigned short* gb_  = (unsigned short*)(ws + 8388608);
  unsigned short* hdb  = (unsigned short*)(ws + 8650752);
  float* g_master      = (float*)(ws + 8912896);
  unsigned int* barcnt = (unsigned int*)(ws + 9437184);
  const size_t FIXED = 9453568ULL;

  int Tc = 64;
  while (Tc > 1 && FIXED + (size_t)Tc * (262144ULL + 2097152ULL) > ws_size) Tc >>= 1;
  unsigned short* xb = (unsigned short*)(ws + FIXED);
  float* XPc = (float*)(ws + FIXED + (size_t)Tc * 262144ULL);

  float* hs = (float*)d_out;
  float* h_tail = hs + (size_t)Tn * Bn * Hn;
  float* g_tail = h_tail + (size_t)Bn * Hn;

  hipMemsetAsync(barcnt, 0, 16384, stream);
  cvt_kernel<<<dim3(512), 256, 0, stream>>>(Wh, Whb, 1536 * 512);
  cvt_kernel<<<dim3(512), 256, 0, stream>>>(Wgh, Wghb, 1536 * 512);
  cvt_kernel<<<dim3(512), 256, 0, stream>>>(Whd, Whdb, 1536 * 512);
  cvt_kernel<<<dim3(512), 256, 0, stream>>>(Wg, Wgb, 1024 * 512);
  cvt_kernel<<<dim3(512), 256, 0, stream>>>(Wx, Wxb, 2048 * 512);
  cvt_kernel<<<dim3(128), 256, 0, stream>>>(h0, hb0, Bn * Hn);
  cvt_kernel<<<dim3(128), 256, 0, stream>>>(g0, gb_, Bn * Hn);

  const int nChunks = Tn / Tc;
  for (int c = 0; c < nChunks; ++c) {
    const int t0 = c * Tc;
    cvt_kernel<<<dim3(1024), 256, 0, stream>>>(x + (size_t)t0 * Bn * INn, xb,
                                               Tc * Bn * INn);
    xp_gemm_kernel<<<dim3(Tc * 4, 32), 256, 0, stream>>>(xb, Wxb, bx, bh, bgh, XPc);
    persist_kernel<<<dim3(256), dim3(TPB), 0, stream>>>(
        Whb, Wghb, Whdb, Wgb, XPc, bhd, bg, hb0, gb_, hdb, g_master, h0, g0,
        hs, h_tail, g_tail, barcnt + c * 8, t0, Tc);
  }
}

// Round 4
// 9087.521 us; speedup vs baseline: 9.5499x; 1.0829x over previous
//
#include <hip/hip_runtime.h>

#define Tn 512
#define Bn 256
#define Hn 512
#define INn 512
#define TPB 512

typedef __attribute__((ext_vector_type(8))) short bf16x8;
typedef __attribute__((ext_vector_type(4))) float f32x4;

__device__ __forceinline__ unsigned short f2bf(float f) {
  unsigned int u = __float_as_uint(f);
  unsigned int r = (u + 0x7fffu + ((u >> 16) & 1u)) >> 16;
  return (unsigned short)r;
}
__device__ __forceinline__ float bf2f(unsigned short u) {
  return __uint_as_float(((unsigned int)u) << 16);
}

__device__ __forceinline__ float sigm(float x) { return 1.0f / (1.0f + __expf(-x)); }
__device__ __forceinline__ float tanh_f(float x) { return 2.0f / (1.0f + __expf(-2.0f * x)) - 1.0f; }

__device__ __forceinline__ bf16x8 ld8(const unsigned short* p) {
  return *reinterpret_cast<const bf16x8*>(p);
}

// coherent LLC-homed ops (sc0 sc1, no cache maintenance)
__device__ __forceinline__ unsigned long long ald8(const unsigned short* p) {
  return __hip_atomic_load((const unsigned long long*)p, __ATOMIC_RELAXED,
                           __HIP_MEMORY_SCOPE_AGENT);
}
__device__ __forceinline__ void ast4(unsigned short* p, unsigned int v) {
  __hip_atomic_store((unsigned int*)p, v, __ATOMIC_RELAXED, __HIP_MEMORY_SCOPE_AGENT);
}

__device__ __forceinline__ f32x4 mfma16(bf16x8 a, bf16x8 b, f32x4 c) {
  return __builtin_amdgcn_mfma_f32_16x16x32_bf16(a, b, c, 0, 0, 0);
}

// ---------------- fp32 -> bf16 conversion ----------------
__global__ __launch_bounds__(256) void cvt_kernel(const float* __restrict__ in,
                                                  unsigned short* __restrict__ out, int n) {
  const int stride = gridDim.x * blockDim.x * 4;
  for (int i = (blockIdx.x * blockDim.x + threadIdx.x) * 4; i < n; i += stride) {
    float4 v = *reinterpret_cast<const float4*>(in + i);
    ushort4 o;
    o.x = f2bf(v.x); o.y = f2bf(v.y); o.z = f2bf(v.z); o.w = f2bf(v.w);
    *reinterpret_cast<ushort4*>(out + i) = o;
  }
}

// ---------------- XP = x @ Wx.T + folded biases, bf16 block-tiled output ----------
// XPb tile for (tt, grp, jblk): 2048 bf16 = [gate(4)][bl(32)][jl(16)], contiguous 4KB.
__global__ __launch_bounds__(256) void xp_gemm_kernel(
    const unsigned short* __restrict__ xb,
    const unsigned short* __restrict__ Wxb,
    const float* __restrict__ bx,
    const float* __restrict__ bh,
    const float* __restrict__ bgh,
    unsigned short* __restrict__ XPb) {
  const int m0 = blockIdx.x * 64;
  const int n0 = blockIdx.y * 64;
  const int wave = threadIdx.x >> 6;
  const int lane = threadIdx.x & 63;
  const int l15 = lane & 15;
  const int lk = (lane >> 4) * 8;
  const int ro = (wave >> 1) * 32;
  const int co = (wave & 1) * 32;
  const unsigned short* ap = xb + (size_t)(m0 + ro + l15) * INn + lk;
  const unsigned short* bp = Wxb + (size_t)(n0 + co + l15) * INn + lk;
  f32x4 acc[2][2] = {};
  for (int k = 0; k < INn; k += 32) {
    bf16x8 a0 = ld8(ap + k);
    bf16x8 a1 = ld8(ap + 16 * INn + k);
    bf16x8 w0 = ld8(bp + k);
    bf16x8 w1 = ld8(bp + 16 * INn + k);
    acc[0][0] = mfma16(a0, w0, acc[0][0]);
    acc[0][1] = mfma16(a0, w1, acc[0][1]);
    acc[1][0] = mfma16(a1, w0, acc[1][0]);
    acc[1][1] = mfma16(a1, w1, acc[1][1]);
  }
#pragma unroll
  for (int rt = 0; rt < 2; ++rt)
#pragma unroll
    for (int ct = 0; ct < 2; ++ct) {
      const int col = n0 + co + ct * 16 + l15;
      const int gate = col >> 9, jcol = col & 511;
      const int jb = jcol >> 4, jl = jcol & 15;
      float bias = bx[col];
      if (col < 1024) bias += bh[col] + bgh[col];
      else if (col >= 1536) bias += bh[col - 512] + bgh[col - 512];
#pragma unroll
      for (int r = 0; r < 4; ++r) {
        const int row = m0 + ro + rt * 16 + (lane >> 4) * 4 + r;
        const int ttl = row >> 8, bb = row & 255;
        XPb[(((size_t)ttl * 8 + (bb >> 5)) * 32 + jb) * 2048 +
            gate * 512 + (bb & 31) * 16 + jl] = f2bf(acc[rt][ct][r] + bias);
      }
    }
}

// ---------------- persistent recurrence kernel ----------------
// Flag barrier: each block stores its epoch to a distinct LLC slot; wave0's
// 32 lanes poll the 32 peers in parallel. No same-address RMW contention.
__device__ __forceinline__ void group_barrier(unsigned int* gflags, int jblk,
                                              unsigned int epoch) {
  __syncthreads();  // drains all payload stores (vmcnt0) before signal
  if (threadIdx.x < 64) {
    if (threadIdx.x == 0)
      __hip_atomic_store(gflags + jblk, epoch, __ATOMIC_RELAXED,
                         __HIP_MEMORY_SCOPE_AGENT);
    unsigned int* p = gflags + (threadIdx.x & 31);
    while (__hip_atomic_load(p, __ATOMIC_RELAXED, __HIP_MEMORY_SCOPE_AGENT) < epoch)
      __builtin_amdgcn_s_sleep(1);
  }
  __syncthreads();
}

// stage 32x512 bf16 from coherent buffer into swizzled LDS, 16B-contiguous chunks
__device__ __forceinline__ void stage_A_part(const unsigned short* src,
                                             unsigned short* dst_l, int b0,
                                             int idx0, int stride, int nIter) {
  for (int q = 0; q < nIter; ++q) {
    const int idx = idx0 + q * stride;
    if (idx < 2048) {
      const int rr = idx >> 6, c = idx & 63;
      union { unsigned long long u[2]; uint4 v; } t;
      const unsigned short* s = src + (size_t)(b0 + rr) * Hn + c * 8;
      t.u[0] = ald8(s);
      t.u[1] = ald8(s + 4);
      *reinterpret_cast<uint4*>(reinterpret_cast<char*>(dst_l) + rr * 1024 +
                                ((c * 16) ^ ((rr & 7) << 4))) = t.v;
    }
  }
}

__global__ __launch_bounds__(512, 2) void persist_kernel(
    const unsigned short* __restrict__ Whb,
    const unsigned short* __restrict__ Wghb,
    const unsigned short* __restrict__ Whdb,
    const unsigned short* __restrict__ Wgb,
    const unsigned short* __restrict__ XPb,
    const float* __restrict__ bhd,
    const float* __restrict__ bg,
    unsigned short* __restrict__ hb0,
    unsigned short* __restrict__ gb,
    unsigned short* __restrict__ hdb,
    float* __restrict__ g_master,
    const float* __restrict__ h0,
    const float* __restrict__ g0,
    float* __restrict__ hs,
    float* __restrict__ h_tail,
    float* __restrict__ g_tail,
    unsigned int* __restrict__ flags,
    int t0, int Tc) {
  __shared__ unsigned short Wh_l[48 * 512];    // 48KB swizzled
  __shared__ unsigned short Wgh_l[48 * 512];   // 48KB swizzled
  __shared__ unsigned short As_l[32 * 512];    // 32KB (gb in A, hdb in B)
  __shared__ float pa[8][32][17];              // 17KB
  __shared__ unsigned short xp_ls[2][2048];    // 8KB double-buffered XP tile

  const int tid = threadIdx.x;
  const int grp = blockIdx.x & 7;
  const int jblk = blockIdx.x >> 3;
  const int j0 = jblk * 16;
  const int b0 = grp * 32;
  const int wv = tid >> 6;
  const int lane = tid & 63;
  const int l15 = lane & 15;
  const int lk = (lane >> 4) * 8;
  unsigned int* gflags = flags + grp * 32;

  // ---- stage Wh, Wgh into LDS ----
  for (int i = tid; i < 48 * 64; i += TPB) {
    const int rr = i >> 6, c = i & 63;
    const int grow = (rr >> 4) * 512 + j0 + (rr & 15);
    const int byte = rr * 1024 + ((c * 16) ^ ((rr & 7) << 4));
    *reinterpret_cast<uint4*>(reinterpret_cast<char*>(Wh_l) + byte) =
        *reinterpret_cast<const uint4*>(Whb + (size_t)grow * 512 + c * 8);
    *reinterpret_cast<uint4*>(reinterpret_cast<char*>(Wgh_l) + byte) =
        *reinterpret_cast<const uint4*>(Wghb + (size_t)grow * 512 + c * 8);
  }

  // ---- per-thread persistent state ----
  const int bl_e = tid >> 4, jl_e = tid & 15;
  const int j_e = j0 + jl_e;
  const size_t o_e = (size_t)(b0 + bl_e) * Hn + j_e;
  float h_m = (t0 == 0) ? h0[o_e] : hs[(size_t)(t0 - 1) * (Bn * Hn) + o_e];
  float g_m = (t0 == 0) ? g0[o_e] : g_master[o_e];
  const float bz2 = bhd[j_e] + bg[j_e];
  const float br2 = bhd[512 + j_e] + bg[512 + j_e];
  const float bgc = bhd[1024 + j_e];
  const int xo = bl_e * 16 + jl_e;

  // preload XP tile for tt=0 (plain cached loads; written by prior kernel)
  {
    const unsigned short* src = XPb + ((size_t)grp * 32 + jblk) * 2048;
    *(unsigned long long*)&xp_ls[0][tid * 4] =
        *(const unsigned long long*)(src + tid * 4);
  }

  // wv0: prefetch hb(t0) into regs (loop-carried across steps)
  unsigned long long rA[16][2][2];
  if (wv == 0) {
    const unsigned short* ap0 =
        hb0 + (size_t)(t0 & 1) * (Bn * Hn) + (size_t)(b0 + l15) * Hn + lk;
#pragma unroll
    for (int kt = 0; kt < 16; ++kt) {
      rA[kt][0][0] = ald8(ap0 + kt * 32);
      rA[kt][0][1] = ald8(ap0 + kt * 32 + 4);
      rA[kt][1][0] = ald8(ap0 + 16 * Hn + kt * 32);
      rA[kt][1][1] = ald8(ap0 + 16 * Hn + kt * 32 + 4);
    }
  }
  __syncthreads();

  unsigned int epoch = 0;
  float z2p = 0.0f, r2p = 0.0f;
  const int swzA = (l15 & 7) << 4;

  for (int tt = 0; tt < Tc; ++tt) {
    const int t = t0 + tt;
    unsigned short* hb_nxt = hb0 + (size_t)((t + 1) & 1) * (Bn * Hn);
    const int cur = tt & 1, nxt = (tt + 1) & 1;

    // ---- pre-phase: waves 1-7 stage gb; waves 3-7 also prefetch XP(t+1) ----
    if (wv >= 1) {
      stage_A_part(gb, As_l, b0, tid - 64, 448, 5);
      if (wv >= 3 && tt + 1 < Tc) {
        const unsigned short* src =
            XPb + (((size_t)(tt + 1) * 8 + grp) * 32 + jblk) * 2048;
        for (int i = tid - 192; i < 512; i += 320)
          *(unsigned long long*)&xp_ls[nxt][i * 4] =
              *(const unsigned long long*)(src + i * 4);
      }
    }
    __syncthreads();

    // ---------- phase A GEMMs ----------
    if (wv == 0) {
      // h @ Wh.T (z,r,u) from prefetched regs
      f32x4 acc[2][3] = {};
#pragma unroll
      for (int kt = 0; kt < 16; ++kt) {
        union { unsigned long long u[2]; bf16x8 v; } a0, a1;
        a0.u[0] = rA[kt][0][0]; a0.u[1] = rA[kt][0][1];
        a1.u[0] = rA[kt][1][0]; a1.u[1] = rA[kt][1][1];
        const int k = kt * 32;
#pragma unroll
        for (int s = 0; s < 3; ++s) {
          const int rr = s * 16 + l15;
          const int byte = rr * 1024 + (((k + lk) * 2) ^ swzA);
          bf16x8 bw = *reinterpret_cast<const bf16x8*>(
              reinterpret_cast<const char*>(Wh_l) + byte);
          acc[0][s] = mfma16(a0.v, bw, acc[0][s]);
          acc[1][s] = mfma16(a1.v, bw, acc[1][s]);
        }
      }
#pragma unroll
      for (int s = 0; s < 3; ++s)
#pragma unroll
        for (int rt = 0; rt < 2; ++rt)
#pragma unroll
          for (int r = 0; r < 4; ++r)
            pa[s][rt * 16 + (lane >> 4) * 4 + r][l15] = acc[rt][s][r];
    } else if (wv == 1) {
      // g @ Wgh.T from staged LDS
      f32x4 acc[2][3] = {};
#pragma unroll
      for (int kt = 0; kt < 16; ++kt) {
        const int k = kt * 32;
        const int abyte = ((k + lk) * 2) ^ swzA;
        bf16x8 a0 = *reinterpret_cast<const bf16x8*>(
            reinterpret_cast<const char*>(As_l) + l15 * 1024 + abyte);
        bf16x8 a1 = *reinterpret_cast<const bf16x8*>(
            reinterpret_cast<const char*>(As_l) + (16 + l15) * 1024 + abyte);
#pragma unroll
        for (int s = 0; s < 3; ++s) {
          const int rr = s * 16 + l15;
          const int byte = rr * 1024 + (((k + lk) * 2) ^ swzA);
          bf16x8 bw = *reinterpret_cast<const bf16x8*>(
              reinterpret_cast<const char*>(Wgh_l) + byte);
          acc[0][s] = mfma16(a0, bw, acc[0][s]);
          acc[1][s] = mfma16(a1, bw, acc[1][s]);
        }
      }
#pragma unroll
      for (int s = 0; s < 3; ++s)
#pragma unroll
        for (int rt = 0; rt < 2; ++rt)
#pragma unroll
          for (int r = 0; r < 4; ++r)
            pa[3 + s][rt * 16 + (lane >> 4) * 4 + r][l15] = acc[rt][s][r];
    } else if (wv == 2) {
      // g @ Wg.T (z2,r2), A from LDS, W streamed from L2
      const unsigned short* bp0 = Wgb + (size_t)(j0 + l15) * Hn + lk;
      const unsigned short* bp1 = Wgb + (size_t)(512 + j0 + l15) * Hn + lk;
      f32x4 acc[2][2] = {};
#pragma unroll
      for (int kt = 0; kt < 16; ++kt) {
        const int k = kt * 32;
        const int abyte = ((k + lk) * 2) ^ swzA;
        bf16x8 a0 = *reinterpret_cast<const bf16x8*>(
            reinterpret_cast<const char*>(As_l) + l15 * 1024 + abyte);
        bf16x8 a1 = *reinterpret_cast<const bf16x8*>(
            reinterpret_cast<const char*>(As_l) + (16 + l15) * 1024 + abyte);
        bf16x8 w0 = ld8(bp0 + k);
        bf16x8 w1 = ld8(bp1 + k);
        acc[0][0] = mfma16(a0, w0, acc[0][0]);
        acc[1][0] = mfma16(a1, w0, acc[1][0]);
        acc[0][1] = mfma16(a0, w1, acc[0][1]);
        acc[1][1] = mfma16(a1, w1, acc[1][1]);
      }
#pragma unroll
      for (int s = 0; s < 2; ++s)
#pragma unroll
        for (int rt = 0; rt < 2; ++rt)
#pragma unroll
          for (int r = 0; r < 4; ++r)
            pa[6 + s][rt * 16 + (lane >> 4) * 4 + r][l15] = acc[rt][s][r];
    }
    __syncthreads();

    // ---------- elementwise h update ----------
    {
      const float z = sigm(bf2f(xp_ls[cur][xo]) + pa[0][bl_e][jl_e] + pa[3][bl_e][jl_e]);
      const float r = sigm(bf2f(xp_ls[cur][512 + xo]) + pa[1][bl_e][jl_e] + pa[4][bl_e][jl_e]);
      const float u = sigm(bf2f(xp_ls[cur][1536 + xo]) + pa[2][bl_e][jl_e] + pa[5][bl_e][jl_e]);
      const float cand = tanh_f(bf2f(xp_ls[cur][1024 + xo]) + r * h_m + u * g_m);
      const float hn = (1.0f - z) * h_m + z * cand;
      const float hd = hn - h_m;
      hs[(size_t)t * (Bn * Hn) + o_e] = hn;
      if (t == Tn - 1) h_tail[o_e] = hn;
      const unsigned int hn_u = f2bf(hn), hd_u = f2bf(hd);
      const unsigned int hn_hi = (unsigned int)__shfl_down((int)hn_u, 1);
      const unsigned int hd_hi = (unsigned int)__shfl_down((int)hd_u, 1);
      if ((jl_e & 1) == 0) {
        ast4(hb_nxt + o_e, hn_u | (hn_hi << 16));
        ast4(hdb + o_e, hd_u | (hd_hi << 16));
      }
      h_m = hn;
      z2p = pa[6][bl_e][jl_e];
      r2p = pa[7][bl_e][jl_e];
    }
    group_barrier(gflags, jblk, ++epoch);

    // ---- stage hd into LDS (all threads) ----
    stage_A_part(hdb, As_l, b0, tid, 512, 4);
    __syncthreads();

    // ---------- phase B GEMMs: hd @ Whd.T (W streamed from L2) ----------
    if (wv < 3) {
      const unsigned short* bp0 = Whdb + (size_t)(wv * 512 + j0 + l15) * Hn + lk;
      f32x4 acc[2] = {};
#pragma unroll
      for (int kt = 0; kt < 16; ++kt) {
        const int k = kt * 32;
        const int abyte = ((k + lk) * 2) ^ swzA;
        bf16x8 a0 = *reinterpret_cast<const bf16x8*>(
            reinterpret_cast<const char*>(As_l) + l15 * 1024 + abyte);
        bf16x8 a1 = *reinterpret_cast<const bf16x8*>(
            reinterpret_cast<const char*>(As_l) + (16 + l15) * 1024 + abyte);
        bf16x8 w0 = ld8(bp0 + k);
        acc[0] = mfma16(a0, w0, acc[0]);
        acc[1] = mfma16(a1, w0, acc[1]);
      }
#pragma unroll
      for (int rt = 0; rt < 2; ++rt)
#pragma unroll
        for (int r = 0; r < 4; ++r)
          pa[wv][rt * 16 + (lane >> 4) * 4 + r][l15] = acc[rt][r];
    }
    // wv0: issue next step's hb prefetch (hb_nxt fully written since barrier1)
    if (wv == 0 && tt + 1 < Tc) {
      const unsigned short* ap0 = hb_nxt + (size_t)(b0 + l15) * Hn + lk;
#pragma unroll
      for (int kt = 0; kt < 16; ++kt) {
        rA[kt][0][0] = ald8(ap0 + kt * 32);
        rA[kt][0][1] = ald8(ap0 + kt * 32 + 4);
        rA[kt][1][0] = ald8(ap0 + 16 * Hn + kt * 32);
        rA[kt][1][1] = ald8(ap0 + 16 * Hn + kt * 32 + 4);
      }
    }
    __syncthreads();

    // ---------- elementwise g update ----------
    {
      const float z2 = sigm(pa[0][bl_e][jl_e] + z2p + bz2);
      const float r2 = sigm(pa[1][bl_e][jl_e] + r2p + br2);
      const float gc = tanh_f(pa[2][bl_e][jl_e] + bgc + r2 * g_m);
      const float gn = (1.0f - z2) * g_m + z2 * gc;
      g_m = gn;
      if (t == Tn - 1) g_tail[o_e] = gn;
      const unsigned int gn_u = f2bf(gn);
      const unsigned int gn_hi = (unsigned int)__shfl_down((int)gn_u, 1);
      if ((jl_e & 1) == 0) ast4(gb + o_e, gn_u | (gn_hi << 16));
    }
    group_barrier(gflags, jblk, ++epoch);
  }
  g_master[o_e] = g_m;
}

// ---------------- host ----------------
extern "C" void kernel_launch(void* const* d_in, const int* in_sizes, int n_in,
                              void* d_out, int out_size, void* d_ws, size_t ws_size,
                              hipStream_t stream) {
  const float* x   = (const float*)d_in[0];
  const float* h0  = (const float*)d_in[1];
  const float* g0  = (const float*)d_in[2];
  const float* Wx  = (const float*)d_in[3];
  const float* bx  = (const float*)d_in[4];
  const float* Wh  = (const float*)d_in[5];
  const float* bh  = (const float*)d_in[6];
  const float* Wgh = (const float*)d_in[7];
  const float* bgh = (const float*)d_in[8];
  const float* Whd = (const float*)d_in[9];
  const float* bhd = (const float*)d_in[10];
  const float* Wg  = (const float*)d_in[11];
  const float* bg  = (const float*)d_in[12];

  char* ws = (char*)d_ws;
  unsigned short* Whb  = (unsigned short*)(ws + 0);
  unsigned short* Wghb = (unsigned short*)(ws + 1572864);
  unsigned short* Whdb = (unsigned short*)(ws + 3145728);
  unsigned short* Wgb  = (unsigned short*)(ws + 4718592);
  unsigned short* Wxb  = (unsigned short*)(ws + 5767168);
  unsigned short* hb0  = (unsigned short*)(ws + 7864320);   // 2 x 256x512
  unsigned short* gb_  = (unsigned short*)(ws + 8388608);
  unsigned short* hdb  = (unsigned short*)(ws + 8650752);
  float* g_master      = (float*)(ws + 8912896);
  unsigned int* flags  = (unsigned int*)(ws + 9437184);     // 16KB
  const size_t FIXED = 9453568ULL;

  int Tc = 64;
  while (Tc > 1 && FIXED + (size_t)Tc * (262144ULL + 1048576ULL) > ws_size) Tc >>= 1;
  unsigned short* xb  = (unsigned short*)(ws + FIXED);
  unsigned short* XPb = (unsigned short*)(ws + FIXED + (size_t)Tc * 262144ULL);

  float* hs = (float*)d_out;
  float* h_tail = hs + (size_t)Tn * Bn * Hn;
  float* g_tail = h_tail + (size_t)Bn * Hn;

  hipMemsetAsync(flags, 0, 16384, stream);
  cvt_kernel<<<dim3(512), 256, 0, stream>>>(Wh, Whb, 1536 * 512);
  cvt_kernel<<<dim3(512), 256, 0, stream>>>(Wgh, Wghb, 1536 * 512);
  cvt_kernel<<<dim3(512), 256, 0, stream>>>(Whd, Whdb, 1536 * 512);
  cvt_kernel<<<dim3(512), 256, 0, stream>>>(Wg, Wgb, 1024 * 512);
  cvt_kernel<<<dim3(512), 256, 0, stream>>>(Wx, Wxb, 2048 * 512);
  cvt_kernel<<<dim3(128), 256, 0, stream>>>(h0, hb0, Bn * Hn);
  cvt_kernel<<<dim3(128), 256, 0, stream>>>(g0, gb_, Bn * Hn);

  const int nChunks = Tn / Tc;
  for (int c = 0; c < nChunks; ++c) {
    const int t0 = c * Tc;
    cvt_kernel<<<dim3(1024), 256, 0, stream>>>(x + (size_t)t0 * Bn * INn, xb,
                                               Tc * Bn * INn);
    xp_gemm_kernel<<<dim3(Tc * 4, 32), 256, 0, stream>>>(xb, Wxb, bx, bh, bgh, XPb);
    persist_kernel<<<dim3(256), dim3(TPB), 0, stream>>>(
        Whb, Wghb, Whdb, Wgb, XPb, bhd, bg, hb0, gb_, hdb, g_master, h0, g0,
        hs, h_tail, g_tail, flags + c * 256, t0, Tc);
  }
}